// Round 1
// baseline (219.904 us; speedup 1.0000x reference)
//
#include <hip/hip_runtime.h>

// ---------------------------------------------------------------------------
// DoReFa BasicBlock on MI355X: both 3x3 convs as exact int8 implicit GEMM.
//   acts   quantized to a_int in {0..3}       (value = a_int/3)
//   weights quantized to w_int in {-3,-1,1,3} (value = w_int/3)
//   conv_f32 = (sum a_int*w_int) / 9  -> folded into BN scale s = inv/9.
// Workspace layout (bytes):
//   [0..8)      : uint maxbits for |w1|,|w2| (atomicMax; memset-0 each call)
//   [1024..2048): s1 float[256]   [2048..3072): t1
//   [3072..4096): s2              [4096..5120): t2
//   [8192)                 : a1 padded NHWC u8 [64][30][30][256]  (14745600 B)
//   [8192+ABUF)            : a2 same
//   [8192+2*ABUF)          : wq1 i8 [256][9*256]   (589824 B)
//   [8192+2*ABUF+589824)   : wq2
// Total ~30.7 MB. Borders of a1/a2 provide conv zero-padding (memset).
// ---------------------------------------------------------------------------

#define ABUF 14745600
using i32x4 = __attribute__((ext_vector_type(4))) int;

__device__ __forceinline__ void gload16(const void* g, void* l) {
  typedef const __attribute__((address_space(1))) unsigned int* gp_t;
  typedef __attribute__((address_space(3))) unsigned int* lp_t;
  __builtin_amdgcn_global_load_lds((gp_t)g, (lp_t)l, 16, 0, 0);
}

// ---- BN constant prep: s = gamma/sqrt(var+eps)/9, t = beta - mean*inv -----
__global__ void prep_bn(const float* g1, const float* b1, const float* m1, const float* v1,
                        const float* g2, const float* b2, const float* m2, const float* v2,
                        float* s1, float* t1, float* s2, float* t2) {
  int c = threadIdx.x;
  float i1 = g1[c] / sqrtf(v1[c] + 1e-5f);
  s1[c] = i1 * (1.f / 9.f);
  t1[c] = b1[c] - m1[c] * i1;
  float i2 = g2[c] / sqrtf(v2[c] + 1e-5f);
  s2[c] = i2 * (1.f / 9.f);
  t2[c] = b2[c] - m2[c] * i2;
}

// ---- max|w| over each weight tensor (tanh monotone: do tanh once later) ---
__global__ void maxabs_k(const float* __restrict__ w1, const float* __restrict__ w2,
                         unsigned* mx) {
  const float4* v = (const float4*)(blockIdx.y ? w2 : w1);
  float loc = 0.f;
  for (int i = blockIdx.x * 256 + threadIdx.x; i < 147456; i += 65536) {
    float4 f = v[i];
    loc = fmaxf(loc, fmaxf(fmaxf(fabsf(f.x), fabsf(f.y)), fmaxf(fabsf(f.z), fabsf(f.w))));
  }
  #pragma unroll
  for (int off = 32; off; off >>= 1) loc = fmaxf(loc, __shfl_xor(loc, off));
  __shared__ float red[4];
  if ((threadIdx.x & 63) == 0) red[threadIdx.x >> 6] = loc;
  __syncthreads();
  if (threadIdx.x == 0) {
    loc = fmaxf(fmaxf(red[0], red[1]), fmaxf(red[2], red[3]));
    atomicMax(&mx[blockIdx.y], __float_as_uint(loc));
  }
}

// ---- weight quantize: OIHW f32 -> [O][tap][I] i8, w_int = 2*round(3t)-3 ---
__global__ void wquant_k(const float* __restrict__ w1, const float* __restrict__ w2,
                         const unsigned* __restrict__ mx,
                         signed char* __restrict__ wq1, signed char* __restrict__ wq2) {
  const float* w = blockIdx.y ? w2 : w1;
  signed char* o = blockIdx.y ? wq2 : wq1;
  int idx = blockIdx.x * 256 + threadIdx.x;           // output index [o][t9][ci]
  int oo = idx / 2304, rr = idx % 2304, t9 = rr >> 8, ci = rr & 255;
  float mt = tanhf(__uint_as_float(mx[blockIdx.y]));
  float t = tanhf(w[oo * 2304 + ci * 9 + t9]) / (2.f * mt) + 0.5f;
  int q = (int)rintf(t * 3.f);                        // rintf = round-half-even = jnp.round
  o[idx] = (signed char)(2 * q - 3);
}

// ---- act quantize + NCHW -> padded NHWC i8 transpose (one (n,h) row/block) -
__global__ void aquant_k(const float* __restrict__ x, unsigned char* __restrict__ a1) {
  int n = blockIdx.x / 28, h = blockIdx.x % 28;
  __shared__ __align__(16) unsigned char l[28 * 256];
  int c = threadIdx.x;
  const float4* src = (const float4*)(x + (size_t)(n * 256 + c) * 784 + h * 28);
  #pragma unroll
  for (int i = 0; i < 7; ++i) {
    float4 f = src[i];
    int p = i * 4;
    l[(p + 0) * 256 + c] = (unsigned char)(int)rintf(3.f * fminf(fmaxf(f.x, 0.f), 1.f));
    l[(p + 1) * 256 + c] = (unsigned char)(int)rintf(3.f * fminf(fmaxf(f.y, 0.f), 1.f));
    l[(p + 2) * 256 + c] = (unsigned char)(int)rintf(3.f * fminf(fmaxf(f.z, 0.f), 1.f));
    l[(p + 3) * 256 + c] = (unsigned char)(int)rintf(3.f * fminf(fmaxf(f.w, 0.f), 1.f));
  }
  __syncthreads();
  if (threadIdx.x < 224) {
    int p = threadIdx.x >> 3, q = threadIdx.x & 7;
    const uint4* s = (const uint4*)&l[p * 256 + q * 32];
    uint4 v0 = s[0], v1 = s[1];
    unsigned char* dst = a1 + ((size_t)((n * 30 + h + 1) * 30) + (p + 1)) * 256 + q * 32;
    ((uint4*)dst)[0] = v0;
    ((uint4*)dst)[1] = v1;
  }
}

// ---- conv as implicit GEMM, int8 MFMA -------------------------------------
// MODE 0: A=act pixels (M), B=weights (N). Epilogue: BN1+ReLU+quant -> a2 NHWC.
// MODE 1: A=weights (M=c_out), B=act pixels (N). Epilogue: BN2+residual+ReLU
//         -> f32 NCHW (D cols = pixels => coalesced writes & residual reads).
// Tile 128x128, BK=128 (2 taps' half / full-half of a tap), 4 waves of 64x64.
// LDS [row][128B] with k16-slot XOR (row&7) swizzle; staged via
// global_load_lds(16B) with inverse-swizzled per-lane global addresses.
template <int MODE>
__global__ __launch_bounds__(256, 2) void conv_gemm(
    const unsigned char* __restrict__ act, const signed char* __restrict__ wq,
    const float* __restrict__ sC, const float* __restrict__ tC,
    const float* __restrict__ xres, unsigned char* __restrict__ actout,
    float* __restrict__ fout) {
  __shared__ __align__(16) unsigned char lds[32768];  // [0,16K)=act, [16K,32K)=w
  const int tid = threadIdx.x;
  const int wv = tid >> 6, lane = tid & 63;
  const int pixBase = blockIdx.x * 128;
  const int wchBase = blockIdx.y * 128;

  // staging precompute: each wave stages rows [wv*32, wv*32+32), 4 calls x 8 rows
  int pA[4];
  const signed char* wp[4];
  #pragma unroll
  for (int c = 0; c < 4; ++c) {
    int row = wv * 32 + c * 8 + (lane >> 3);
    int k16 = ((lane & 7) ^ (row & 7)) << 4;  // inverse-swizzled source slot
    int m = pixBase + row;
    int n = m / 784, rem = m % 784;
    int hh = rem / 28, ww = rem % 28;
    pA[c] = (((n * 30 + hh) * 30 + ww) << 8) + k16;   // + tapoff + cib later
    wp[c] = wq + (wchBase + row) * 2304 + k16;
  }

  i32x4 acc[4][4];
  #pragma unroll
  for (int i = 0; i < 4; ++i)
    #pragma unroll
    for (int j = 0; j < 4; ++j) acc[i][j] = (i32x4){0, 0, 0, 0};

  const int prow_off = (MODE == 0) ? (wv & 1) * 64 : (wv >> 1) * 64;  // pixel frag rows
  const int wrow_off = (MODE == 0) ? (wv >> 1) * 64 : (wv & 1) * 64;  // c_out frag rows

  for (int ks = 0; ks < 18; ++ks) {
    const int tap = ks >> 1;
    const int toff = (((tap / 3) * 30 + (tap % 3)) << 8) + ((ks & 1) << 7);
    #pragma unroll
    for (int c = 0; c < 4; ++c) {
      gload16(act + pA[c] + toff, &lds[wv * 4096 + c * 1024]);
      gload16(wp[c] + ks * 128, &lds[16384 + wv * 4096 + c * 1024]);
    }
    __syncthreads();  // compiler emits vmcnt(0) drain before barrier

    i32x4 pf[4][2], wf[4][2];
    #pragma unroll
    for (int f = 0; f < 4; ++f) {
      #pragma unroll
      for (int kc = 0; kc < 2; ++kc) {
        int sl = kc * 4 + (lane >> 4);
        int rp = prow_off + f * 16 + (lane & 15);
        pf[f][kc] = *(const i32x4*)&lds[rp * 128 + ((sl ^ (rp & 7)) << 4)];
        int rw = wrow_off + f * 16 + (lane & 15);
        wf[f][kc] = *(const i32x4*)&lds[16384 + rw * 128 + ((sl ^ (rw & 7)) << 4)];
      }
    }
    #pragma unroll
    for (int kc = 0; kc < 2; ++kc)
      #pragma unroll
      for (int i = 0; i < 4; ++i)
        #pragma unroll
        for (int j = 0; j < 4; ++j) {
          if (MODE == 0)
            acc[i][j] = __builtin_amdgcn_mfma_i32_16x16x64_i8(pf[i][kc], wf[j][kc], acc[i][j], 0, 0, 0);
          else
            acc[i][j] = __builtin_amdgcn_mfma_i32_16x16x64_i8(wf[i][kc], pf[j][kc], acc[i][j], 0, 0, 0);
        }
    __syncthreads();
  }

  if (MODE == 0) {
    // D: row=(lane>>4)*4+r = pixel, col=lane&15 = c_out
    #pragma unroll
    for (int j = 0; j < 4; ++j) {
      int c = wchBase + wrow_off + j * 16 + (lane & 15);
      float s = sC[c], t = tC[c];
      #pragma unroll
      for (int i = 0; i < 4; ++i) {
        #pragma unroll
        for (int r = 0; r < 4; ++r) {
          int m = pixBase + prow_off + i * 16 + ((lane >> 4) << 2) + r;
          int n = m / 784, rem = m % 784, hh = rem / 28, ww = rem % 28;
          float y = (float)acc[i][j][r] * s + t;       // BN1
          y = fminf(fmaxf(y, 0.f), 1.f);               // ReLU + clamp01
          actout[((n * 30 + hh + 1) * 30 + (ww + 1)) * 256 + c] =
              (unsigned char)(int)rintf(y * 3.f);      // 2-bit requant
        }
      }
    }
  } else {
    // D: row = c_out, col = pixel (coalesced along w)
    #pragma unroll
    for (int i = 0; i < 4; ++i) {
      #pragma unroll
      for (int r = 0; r < 4; ++r) {
        int c = wchBase + wrow_off + i * 16 + ((lane >> 4) << 2) + r;
        float s = sC[c], t = tC[c];
        #pragma unroll
        for (int j = 0; j < 4; ++j) {
          int m = pixBase + prow_off + j * 16 + (lane & 15);
          int n = m / 784, rem = m % 784;
          int addr = n * 200704 + c * 784 + rem;
          float y = (float)acc[i][j][r] * s + t + xres[addr];  // BN2 + residual
          fout[addr] = fmaxf(y, 0.f);                          // final ReLU
        }
      }
    }
  }
}

extern "C" void kernel_launch(void* const* d_in, const int* in_sizes, int n_in,
                              void* d_out, int out_size, void* d_ws, size_t ws_size,
                              hipStream_t stream) {
  const float* x  = (const float*)d_in[0];
  const float* w1 = (const float*)d_in[1];
  const float* g1 = (const float*)d_in[2];
  const float* b1 = (const float*)d_in[3];
  const float* m1 = (const float*)d_in[4];
  const float* v1 = (const float*)d_in[5];
  const float* w2 = (const float*)d_in[6];
  const float* g2 = (const float*)d_in[7];
  const float* b2 = (const float*)d_in[8];
  const float* m2 = (const float*)d_in[9];
  const float* v2 = (const float*)d_in[10];

  char* ws = (char*)d_ws;
  unsigned* mx = (unsigned*)ws;
  float* s1 = (float*)(ws + 1024);
  float* t1 = (float*)(ws + 2048);
  float* s2 = (float*)(ws + 3072);
  float* t2 = (float*)(ws + 4096);
  unsigned char* a1 = (unsigned char*)(ws + 8192);
  unsigned char* a2 = a1 + ABUF;
  signed char* wq1 = (signed char*)(a2 + ABUF);
  signed char* wq2 = wq1 + 589824;

  // zero: atomicMax slots + both padded act buffers (conv zero-padding)
  hipMemsetAsync(ws, 0, 8192 + 2 * (size_t)ABUF, stream);
  prep_bn<<<1, 256, 0, stream>>>(g1, b1, m1, v1, g2, b2, m2, v2, s1, t1, s2, t2);
  maxabs_k<<<dim3(256, 2), 256, 0, stream>>>(w1, w2, mx);
  wquant_k<<<dim3(2304, 2), 256, 0, stream>>>(w1, w2, mx, wq1, wq2);
  aquant_k<<<64 * 28, 256, 0, stream>>>(x, a1);
  conv_gemm<0><<<dim3(392, 2), 256, 0, stream>>>(a1, wq1, s1, t1, nullptr, a2, nullptr);
  conv_gemm<1><<<dim3(392, 2), 256, 0, stream>>>(a2, wq2, s2, t2, x, nullptr, (float*)d_out);
}